// Round 2
// baseline (300.347 us; speedup 1.0000x reference)
//
#include <hip/hip_runtime.h>
#include <stdint.h>

typedef __bf16 bf16_t;
typedef __bf16 bf16x8 __attribute__((ext_vector_type(8)));
typedef __bf16 bf16x4 __attribute__((ext_vector_type(4)));
typedef float  f32x4  __attribute__((ext_vector_type(4)));

#define AS1 __attribute__((address_space(1)))
#define AS3 __attribute__((address_space(3)))

#define SEQ   4096
#define DIMM  512
#define DIN   1024
#define ROWS  16384   // BATCH*SEQLEN

__device__ __forceinline__ void gload_lds16(const void* g, void* l) {
  __builtin_amdgcn_global_load_lds((AS1 void*)g, (AS3 void*)l, 16, 0, 0);
}

// ---------------- C = A (MxK, lda) * B^T (NxK packed), bf16 in, fp32 acc ----------------
// 128x128 tile, BK=64, 256 threads (4 waves, 2x2 of 64x64), mfma 16x16x32 bf16
template<bool OUT_BF16>
__global__ void gemm_bt(const bf16_t* __restrict__ A, const bf16_t* __restrict__ B,
                        void* __restrict__ Cv, int lda, int N, int K)
{
  __shared__ __align__(16) bf16_t As[128*64];
  __shared__ __align__(16) bf16_t Bs[128*64];
  const int tid = threadIdx.x;
  const int l = tid & 63, w = tid >> 6;
  const int bm = blockIdx.x, bn = blockIdx.y;
  const bf16_t* Ab = A + (size_t)bm*128*lda;
  const bf16_t* Bb = B + (size_t)bn*128*K;
  f32x4 acc[4][4] = {};
  const int wr = (w>>1)*64, wc = (w&1)*64;
  const int lr = l & 15, lk = (l>>4)*8;
  const int srow = w*8 + (l>>3);   // row within each 32-row staging group
  const int scol = (l&7)*8;        // col (elements) within 64-wide K slice

  for (int kt = 0; kt < K; kt += 64) {
#pragma unroll
    for (int i = 0; i < 4; i++) {
      gload_lds16(Ab + (size_t)(i*32 + srow)*lda + kt + scol, As + i*2048 + w*512);
      gload_lds16(Bb + (size_t)(i*32 + srow)*K   + kt + scol, Bs + i*2048 + w*512);
    }
    __syncthreads();
#pragma unroll
    for (int kk = 0; kk < 2; kk++) {
      bf16x8 af[4], bv[4];
#pragma unroll
      for (int m = 0; m < 4; m++) af[m] = *(const bf16x8*)&As[(wr + m*16 + lr)*64 + kk*32 + lk];
#pragma unroll
      for (int n = 0; n < 4; n++) bv[n] = *(const bf16x8*)&Bs[(wc + n*16 + lr)*64 + kk*32 + lk];
#pragma unroll
      for (int m = 0; m < 4; m++)
#pragma unroll
        for (int n = 0; n < 4; n++)
          acc[m][n] = __builtin_amdgcn_mfma_f32_16x16x32_bf16(af[m], bv[n], acc[m][n], 0, 0, 0);
    }
    __syncthreads();
  }
  const int row0 = bm*128 + wr + (l>>4)*4;
  const int col0 = bn*128 + wc + lr;
#pragma unroll
  for (int m = 0; m < 4; m++)
#pragma unroll
    for (int n = 0; n < 4; n++)
#pragma unroll
      for (int r = 0; r < 4; r++) {
        size_t idx = (size_t)(row0 + m*16 + r)*N + (col0 + n*16);
        if constexpr (OUT_BF16) ((bf16_t*)Cv)[idx] = (bf16_t)acc[m][n][r];
        else                    ((float*)Cv)[idx]  = acc[m][n][r];
      }
}

// ---------------- fp32 -> bf16 conversions + packed W_dt/W_x[16:32] ----------------
__global__ __launch_bounds__(256) void convert_kernel(
    const float* __restrict__ x, const float* __restrict__ W_in,
    const float* __restrict__ W_out, const float* __restrict__ W_dt, const float* __restrict__ W_x,
    bf16_t* __restrict__ x_bf, bf16_t* __restrict__ Win_bf,
    bf16_t* __restrict__ Wout_bf, bf16_t* __restrict__ Wcat_bf)
{
  const size_t N0 = 8388608/4, N1 = N0 + 1048576/4, N2 = N1 + 524288/4, N3 = N2 + 131072/4;
  size_t i = (size_t)blockIdx.x*256 + threadIdx.x;
  bf16_t* dst; float4 v;
  if (i < N0)      { v = ((const float4*)x)[i];          dst = x_bf   + i*4; }
  else if (i < N1) { size_t j = i - N0; v = ((const float4*)W_in)[j];  dst = Win_bf  + j*4; }
  else if (i < N2) { size_t j = i - N1; v = ((const float4*)W_out)[j]; dst = Wout_bf + j*4; }
  else if (i < N3) {
    size_t j = i - N2; size_t el = j*4; int r = (int)(el >> 10), c = (int)(el & 1023);
    if (r < 16)      v = *(const float4*)(W_dt + r*1024 + c);
    else if (r < 32) v = *(const float4*)(W_x  + r*1024 + c);   // rows 16..31 = B_proj slice
    else             v = make_float4(0.f, 0.f, 0.f, 0.f);
    dst = Wcat_bf + el;
  } else return;
  bf16x4 o; o[0]=(bf16_t)v.x; o[1]=(bf16_t)v.y; o[2]=(bf16_t)v.z; o[3]=(bf16_t)v.w;
  *(bf16x4*)dst = o;
}

// ------------- depthwise causal conv(4) + bias + SiLU + u=mean(xa[:,:64]) -------------
// one wave per row; lane handles 16 contiguous channels
__global__ __launch_bounds__(256) void conv_kernel(
    const bf16_t* __restrict__ xi_res, const float* __restrict__ conv_w,
    const float* __restrict__ conv_b, bf16_t* __restrict__ xa, float* __restrict__ u)
{
  const int row = blockIdx.x*4 + (threadIdx.x >> 6);
  const int l = threadIdx.x & 63;
  const int lb = row & (SEQ - 1);
  const int c0 = l*16;
  float acc[16];
#pragma unroll
  for (int q = 0; q < 4; q++) {
    float4 v = *(const float4*)(conv_b + c0 + q*4);
    acc[q*4+0]=v.x; acc[q*4+1]=v.y; acc[q*4+2]=v.z; acc[q*4+3]=v.w;
  }
  float wgt[16][4];
#pragma unroll
  for (int e = 0; e < 16; e++) {
    float4 v = *(const float4*)(conv_w + (size_t)(c0+e)*4);
    wgt[e][0]=v.x; wgt[e][1]=v.y; wgt[e][2]=v.z; wgt[e][3]=v.w;
  }
#pragma unroll
  for (int k = 0; k < 4; k++) {
    int ls = lb - 3 + k;
    if (ls < 0) continue;
    const bf16_t* xr = xi_res + (size_t)(row - 3 + k)*2048 + c0;
    bf16x8 v0 = *(const bf16x8*)xr;
    bf16x8 v1 = *(const bf16x8*)(xr + 8);
#pragma unroll
    for (int e = 0; e < 8; e++) acc[e]   += (float)v0[e] * wgt[e][k];
#pragma unroll
    for (int e = 0; e < 8; e++) acc[8+e] += (float)v1[e] * wgt[8+e][k];
  }
  bf16x8 o0, o1;
#pragma unroll
  for (int e = 0; e < 16; e++) {
    float v = acc[e];
    float s = v / (1.f + expf(-v));
    acc[e] = s;
    if (e < 8) o0[e] = (bf16_t)s; else o1[e-8] = (bf16_t)s;
  }
  float usum = 0.f;
  if (l < 4) {
#pragma unroll
    for (int e = 0; e < 16; e++) usum += acc[e];
  }
  bf16_t* xw = xa + (size_t)row*DIN + c0;
  *(bf16x8*)xw = o0;
  *(bf16x8*)(xw + 8) = o1;
  usum += __shfl_xor(usum, 1, 64);
  usum += __shfl_xor(usum, 2, 64);
  if (l == 0) u[row] = usum * (1.f/64.f);
}

// ---------------- dt = softplus(proj+b), a = exp(A*dt), Bu = dt*Bp*u ----------------
__global__ __launch_bounds__(256) void dt_kernel(
    const float* __restrict__ proj, const float* __restrict__ u,
    const float* __restrict__ b_dt, const float* __restrict__ A_log, float2* __restrict__ aBu)
{
  int idx = blockIdx.x*256 + threadIdx.x;   // ROWS*16
  int row = idx >> 4, n = idx & 15;
  float xdt = proj[(size_t)row*128 + n] + b_dt[n];
  float dt = (xdt > 20.f) ? xdt : log1pf(expf(xdt));
  float a  = expf(-expf(A_log[n]) * dt);
  float Bu = dt * proj[(size_t)row*128 + 16 + n] * u[row];
  aBu[idx] = make_float2(a, Bu);
}

// ---------------- segmented scan: s = s*a + b over L=4096, per (b,n) ----------------
__global__ __launch_bounds__(64) void scan_kernel(const float2* __restrict__ aBu, float* __restrict__ y)
{
  const int b = blockIdx.x >> 4, n = blockIdx.x & 15;
  const int l = threadIdx.x;
  const float2* base = aBu + (size_t)b*SEQ*16 + n;
  const int t0 = l*64;
  float P = 1.f, S = 0.f;
  for (int s = 0; s < 64; s++) {
    float2 ab = base[(size_t)(t0+s)*16];
    S = S*ab.x + ab.y;
    P *= ab.x;
  }
  float Pi = P, Si = S;
#pragma unroll
  for (int off = 1; off < 64; off <<= 1) {
    float Pp = __shfl_up(Pi, off, 64);
    float Sp = __shfl_up(Si, off, 64);
    if (l >= off) { Si = Sp*Pi + Si; Pi *= Pp; }
  }
  float carry = __shfl_up(Si, 1, 64);
  if (l == 0) carry = 0.f;
  float s = carry;
  float* yb = y + (size_t)b*SEQ*16 + n;
  for (int st = 0; st < 64; st++) {
    float2 ab = base[(size_t)(t0+st)*16];
    s = s*ab.x + ab.y;
    yb[(size_t)(t0+st)*16] = s;
  }
}

// ---------------- y_full = (y_rep + xa*D) * silu(res) -> written into xi half of xi_res ----------------
__global__ __launch_bounds__(256) void yfull_kernel(
    const bf16_t* __restrict__ xa, bf16_t* __restrict__ xi_res,
    const float* __restrict__ y_state, const float* __restrict__ D_param)
{
  int idx = blockIdx.x*256 + threadIdx.x;   // ROWS * 128 chunks of 8
  int row = idx >> 7, cc = (idx & 127)*8;
  bf16x8 xav  = *(const bf16x8*)&xa[(size_t)row*DIN + cc];
  bf16x8 resv = *(const bf16x8*)&xi_res[(size_t)row*2048 + DIN + cc];
  float ys = y_state[(size_t)row*16 + (cc >> 6)];
  float dp[8];
  float4 d0 = *(const float4*)(D_param + cc);
  float4 d1 = *(const float4*)(D_param + cc + 4);
  dp[0]=d0.x; dp[1]=d0.y; dp[2]=d0.z; dp[3]=d0.w; dp[4]=d1.x; dp[5]=d1.y; dp[6]=d1.z; dp[7]=d1.w;
  bf16x8 o;
#pragma unroll
  for (int e = 0; e < 8; e++) {
    float r = (float)resv[e];
    float sil = r / (1.f + expf(-r));
    float yv = (ys + (float)xav[e]*dp[e]) * sil;
    o[e] = (bf16_t)yv;
  }
  *(bf16x8*)&xi_res[(size_t)row*2048 + cc] = o;   // in-place into xi half
}

extern "C" void kernel_launch(void* const* d_in, const int* in_sizes, int n_in,
                              void* d_out, int out_size, void* d_ws, size_t ws_size,
                              hipStream_t stream)
{
  const float* x      = (const float*)d_in[0];
  const float* W_in   = (const float*)d_in[1];
  const float* conv_w = (const float*)d_in[2];
  const float* conv_b = (const float*)d_in[3];
  const float* W_x    = (const float*)d_in[4];
  const float* W_dt   = (const float*)d_in[5];
  const float* b_dt   = (const float*)d_in[6];
  const float* A_log  = (const float*)d_in[7];
  const float* D_param= (const float*)d_in[8];
  const float* W_out  = (const float*)d_in[9];
  float* out = (float*)d_out;
  char* ws = (char*)d_ws;

  if (ws_size < 121700352u) return;  // ~116 MB scratch

  const size_t MB = 1024*1024;
  bf16_t* x_bf    = (bf16_t*)(ws + 0);          // 16 MB, dead after gemm1
  float*  proj    = (float*) (ws + 0);          //  8 MB, overlays x_bf
  float*  y_state = (float*) (ws + 8*MB);       //  1 MB, overlays x_bf
  bf16_t* Win_bf  = (bf16_t*)(ws + 16*MB);      //  2 MB, dead after gemm1
  float2* aBu     = (float2*)(ws + 16*MB);      //  2 MB, overlays Win_bf
  bf16_t* Wout_bf = (bf16_t*)(ws + 18*MB);      //  1 MB
  bf16_t* Wcat_bf = (bf16_t*)(ws + 19*MB);      //  0.25 MB
  bf16_t* xi_res  = (bf16_t*)(ws + 20*MB);      // 64 MB (xi half reused as yfull)
  bf16_t* xa      = (bf16_t*)(ws + 84*MB);      // 32 MB
  float*  u       = (float*) (ws + 116*MB);     // 64 KB

  convert_kernel<<<dim3(9856), dim3(256), 0, stream>>>(x, W_in, W_out, W_dt, W_x,
                                                       x_bf, Win_bf, Wout_bf, Wcat_bf);
  gemm_bt<true ><<<dim3(128,16), dim3(256), 0, stream>>>(x_bf, Win_bf, (void*)xi_res, 512, 2048, 512);
  conv_kernel   <<<dim3(4096), dim3(256), 0, stream>>>(xi_res, conv_w, conv_b, xa, u);
  gemm_bt<false><<<dim3(128,1), dim3(256), 0, stream>>>(xa, Wcat_bf, (void*)proj, 1024, 128, 1024);
  dt_kernel     <<<dim3(1024), dim3(256), 0, stream>>>(proj, u, b_dt, A_log, aBu);
  scan_kernel   <<<dim3(64), dim3(64), 0, stream>>>(aBu, y_state);
  yfull_kernel  <<<dim3(8192), dim3(256), 0, stream>>>(xa, xi_res, y_state, D_param);
  gemm_bt<false><<<dim3(128,4), dim3(256), 0, stream>>>(xi_res, Wout_bf, (void*)out, 2048, 512, 1024);
}

// Round 4
// 249.714 us; speedup vs baseline: 1.2028x; 1.2028x over previous
//
#include <hip/hip_runtime.h>
#include <stdint.h>

typedef __bf16 bf16_t;
typedef __bf16 bf16x8 __attribute__((ext_vector_type(8)));
typedef __bf16 bf16x4 __attribute__((ext_vector_type(4)));
typedef float  f32x4  __attribute__((ext_vector_type(4)));

#define AS1 __attribute__((address_space(1)))
#define AS3 __attribute__((address_space(3)))

#define SEQ   4096
#define DIMM  512
#define DIN   1024
#define ROWS  16384   // BATCH*SEQLEN

__device__ __forceinline__ void gload_lds16(const void* g, void* l) {
  __builtin_amdgcn_global_load_lds((AS1 void*)g, (AS3 void*)l, 16, 0, 0);
}

// ---------------- C = A (MxK, lda) * B^T (NxK packed), bf16 in, fp32 acc ----------------
// 128x128 tile, BK=64, 256 threads (4 waves, 2x2 of 64x64), mfma 16x16x32 bf16
template<bool OUT_BF16>
__global__ void gemm_bt(const bf16_t* __restrict__ A, const bf16_t* __restrict__ B,
                        void* __restrict__ Cv, int lda, int N, int K)
{
  __shared__ __align__(16) bf16_t As[128*64];
  __shared__ __align__(16) bf16_t Bs[128*64];
  const int tid = threadIdx.x;
  const int l = tid & 63, w = tid >> 6;
  const int bm = blockIdx.x, bn = blockIdx.y;
  const bf16_t* Ab = A + (size_t)bm*128*lda;
  const bf16_t* Bb = B + (size_t)bn*128*K;
  f32x4 acc[4][4] = {};
  const int wr = (w>>1)*64, wc = (w&1)*64;
  const int lr = l & 15, lk = (l>>4)*8;
  const int srow = w*8 + (l>>3);   // row within each 32-row staging group
  const int scol = (l&7)*8;        // col (elements) within 64-wide K slice

  for (int kt = 0; kt < K; kt += 64) {
#pragma unroll
    for (int i = 0; i < 4; i++) {
      gload_lds16(Ab + (size_t)(i*32 + srow)*lda + kt + scol, As + i*2048 + w*512);
      gload_lds16(Bb + (size_t)(i*32 + srow)*K   + kt + scol, Bs + i*2048 + w*512);
    }
    __syncthreads();
#pragma unroll
    for (int kk = 0; kk < 2; kk++) {
      bf16x8 af[4], bv[4];
#pragma unroll
      for (int m = 0; m < 4; m++) af[m] = *(const bf16x8*)&As[(wr + m*16 + lr)*64 + kk*32 + lk];
#pragma unroll
      for (int n = 0; n < 4; n++) bv[n] = *(const bf16x8*)&Bs[(wc + n*16 + lr)*64 + kk*32 + lk];
#pragma unroll
      for (int m = 0; m < 4; m++)
#pragma unroll
        for (int n = 0; n < 4; n++)
          acc[m][n] = __builtin_amdgcn_mfma_f32_16x16x32_bf16(af[m], bv[n], acc[m][n], 0, 0, 0);
    }
    __syncthreads();
  }
  const int row0 = bm*128 + wr + (l>>4)*4;
  const int col0 = bn*128 + wc + lr;
#pragma unroll
  for (int m = 0; m < 4; m++)
#pragma unroll
    for (int n = 0; n < 4; n++)
#pragma unroll
      for (int r = 0; r < 4; r++) {
        size_t idx = (size_t)(row0 + m*16 + r)*N + (col0 + n*16);
        if constexpr (OUT_BF16) ((bf16_t*)Cv)[idx] = (bf16_t)acc[m][n][r];
        else                    ((float*)Cv)[idx]  = acc[m][n][r];
      }
}

// ---------------- fp32 -> bf16 conversions + packed W_dt/W_x[16:32] ----------------
__global__ __launch_bounds__(256) void convert_kernel(
    const float* __restrict__ x, const float* __restrict__ W_in,
    const float* __restrict__ W_out, const float* __restrict__ W_dt, const float* __restrict__ W_x,
    bf16_t* __restrict__ x_bf, bf16_t* __restrict__ Win_bf,
    bf16_t* __restrict__ Wout_bf, bf16_t* __restrict__ Wcat_bf)
{
  const size_t N0 = 8388608/4, N1 = N0 + 1048576/4, N2 = N1 + 524288/4, N3 = N2 + 131072/4;
  size_t i = (size_t)blockIdx.x*256 + threadIdx.x;
  bf16_t* dst; float4 v;
  if (i < N0)      { v = ((const float4*)x)[i];          dst = x_bf   + i*4; }
  else if (i < N1) { size_t j = i - N0; v = ((const float4*)W_in)[j];  dst = Win_bf  + j*4; }
  else if (i < N2) { size_t j = i - N1; v = ((const float4*)W_out)[j]; dst = Wout_bf + j*4; }
  else if (i < N3) {
    size_t j = i - N2; size_t el = j*4; int r = (int)(el >> 10), c = (int)(el & 1023);
    if (r < 16)      v = *(const float4*)(W_dt + r*1024 + c);
    else if (r < 32) v = *(const float4*)(W_x  + r*1024 + c);   // rows 16..31 = B_proj slice
    else             v = make_float4(0.f, 0.f, 0.f, 0.f);
    dst = Wcat_bf + el;
  } else return;
  bf16x4 o; o[0]=(bf16_t)v.x; o[1]=(bf16_t)v.y; o[2]=(bf16_t)v.z; o[3]=(bf16_t)v.w;
  *(bf16x4*)dst = o;
}

// ------------- depthwise causal conv(4) + bias + SiLU + u=mean(xa[:,:64]) -------------
// Team = 128 threads (8 ch/thread, 1024 ch) walking 16 consecutive rows of one batch.
// Weights in registers; xi read exactly once via 4-deep register ring.
// Ring invariant: slot(row index i) = i & 3  (i is row offset from r0; warmup rows
// r0-3,r0-2,r0-1 are i=-3,-2,-1 -> slots 1,2,3).
#define CONV_T 16
__global__ __launch_bounds__(256) void conv_kernel(
    const bf16_t* __restrict__ xi_res, const float* __restrict__ conv_w,
    const float* __restrict__ conv_b, bf16_t* __restrict__ xa, float* __restrict__ u)
{
  const int team = blockIdx.x*2 + (threadIdx.x >> 7);   // 1024 teams
  const int t    = threadIdx.x & 127;
  const int b    = team >> 8;                           // 256 teams per batch
  const int r0   = (team & 255) * CONV_T;               // row within batch
  const int c0   = t * 8;

  float w[8][4], bias[8];
#pragma unroll
  for (int e = 0; e < 8; e++) {
    float4 v = *(const float4*)(conv_w + (size_t)(c0 + e)*4);
    w[e][0]=v.x; w[e][1]=v.y; w[e][2]=v.z; w[e][3]=v.w;
  }
  {
    float4 b0 = *(const float4*)(conv_b + c0);
    float4 b1 = *(const float4*)(conv_b + c0 + 4);
    bias[0]=b0.x; bias[1]=b0.y; bias[2]=b0.z; bias[3]=b0.w;
    bias[4]=b1.x; bias[5]=b1.y; bias[6]=b1.z; bias[7]=b1.w;
  }

  const bf16_t* xbase = xi_res + (size_t)b*SEQ*2048 + c0;
  bf16x8 win[4];
#pragma unroll
  for (int k = 0; k < 4; k++)
#pragma unroll
    for (int e = 0; e < 8; e++) win[k][e] = (bf16_t)0.f;

  // warmup: rows r0-3, r0-2, r0-1 -> slots 1, 2, 3
#pragma unroll
  for (int k = 1; k < 4; k++) {
    int lb = r0 - 4 + k;
    if (lb >= 0) win[k] = *(const bf16x8*)(xbase + (size_t)lb*2048);
  }

  const int growbase = b*SEQ + r0;
#pragma unroll
  for (int i = 0; i < CONV_T; i++) {
    win[i & 3] = *(const bf16x8*)(xbase + (size_t)(r0 + i)*2048);  // row r0+i -> slot i&3
    bf16x8 o;
    float usum = 0.f;
#pragma unroll
    for (int e = 0; e < 8; e++) {
      float acc = bias[e]
        + w[e][0]*(float)win[(i+1)&3][e]   // row r0+i-3
        + w[e][1]*(float)win[(i+2)&3][e]   // row r0+i-2
        + w[e][2]*(float)win[(i+3)&3][e]   // row r0+i-1
        + w[e][3]*(float)win[(i  )&3][e];  // row r0+i
      float sil = acc / (1.f + expf(-acc));
      usum += sil;
      o[e] = (bf16_t)sil;
    }
    *(bf16x8*)(xa + (size_t)(growbase + i)*DIN + c0) = o;
    if (t < 8) {
      usum += __shfl_xor(usum, 1, 64);
      usum += __shfl_xor(usum, 2, 64);
      usum += __shfl_xor(usum, 4, 64);
      if (t == 0) u[growbase + i] = usum * (1.f/64.f);
    }
  }
}

// ---------------- dt = softplus(proj+b), a = exp(A*dt), Bu = dt*Bp*u ----------------
__global__ __launch_bounds__(256) void dt_kernel(
    const float* __restrict__ proj, const float* __restrict__ u,
    const float* __restrict__ b_dt, const float* __restrict__ A_log, float2* __restrict__ aBu)
{
  int idx = blockIdx.x*256 + threadIdx.x;   // ROWS*16
  int row = idx >> 4, n = idx & 15;
  float xdt = proj[(size_t)row*128 + n] + b_dt[n];
  float dt = (xdt > 20.f) ? xdt : log1pf(expf(xdt));
  float a  = expf(-expf(A_log[n]) * dt);
  float Bu = dt * proj[(size_t)row*128 + 16 + n] * u[row];
  aBu[idx] = make_float2(a, Bu);
}

// ---------------- segmented scan: s = s*a + b over L=4096, per (b,n) ----------------
__global__ __launch_bounds__(64) void scan_kernel(const float2* __restrict__ aBu, float* __restrict__ y)
{
  const int b = blockIdx.x >> 4, n = blockIdx.x & 15;
  const int l = threadIdx.x;
  const float2* base = aBu + (size_t)b*SEQ*16 + n;
  const int t0 = l*64;
  float P = 1.f, S = 0.f;
  for (int s = 0; s < 64; s++) {
    float2 ab = base[(size_t)(t0+s)*16];
    S = S*ab.x + ab.y;
    P *= ab.x;
  }
  float Pi = P, Si = S;
#pragma unroll
  for (int off = 1; off < 64; off <<= 1) {
    float Pp = __shfl_up(Pi, off, 64);
    float Sp = __shfl_up(Si, off, 64);
    if (l >= off) { Si = Sp*Pi + Si; Pi *= Pp; }
  }
  float carry = __shfl_up(Si, 1, 64);
  if (l == 0) carry = 0.f;
  float s = carry;
  float* yb = y + (size_t)b*SEQ*16 + n;
  for (int st = 0; st < 64; st++) {
    float2 ab = base[(size_t)(t0+st)*16];
    s = s*ab.x + ab.y;
    yb[(size_t)(t0+st)*16] = s;
  }
}

// ---------------- y_full = (y_rep + xa*D) * silu(res) -> written into xi half of xi_res ----------------
__global__ __launch_bounds__(256) void yfull_kernel(
    const bf16_t* __restrict__ xa, bf16_t* __restrict__ xi_res,
    const float* __restrict__ y_state, const float* __restrict__ D_param)
{
  int idx = blockIdx.x*256 + threadIdx.x;   // ROWS * 128 chunks of 8
  int row = idx >> 7, cc = (idx & 127)*8;
  bf16x8 xav  = *(const bf16x8*)&xa[(size_t)row*DIN + cc];
  bf16x8 resv = *(const bf16x8*)&xi_res[(size_t)row*2048 + DIN + cc];
  float ys = y_state[(size_t)row*16 + (cc >> 6)];
  float dp[8];
  float4 d0 = *(const float4*)(D_param + cc);
  float4 d1 = *(const float4*)(D_param + cc + 4);
  dp[0]=d0.x; dp[1]=d0.y; dp[2]=d0.z; dp[3]=d0.w; dp[4]=d1.x; dp[5]=d1.y; dp[6]=d1.z; dp[7]=d1.w;
  bf16x8 o;
#pragma unroll
  for (int e = 0; e < 8; e++) {
    float r = (float)resv[e];
    float sil = r / (1.f + expf(-r));
    float yv = (ys + (float)xav[e]*dp[e]) * sil;
    o[e] = (bf16_t)yv;
  }
  *(bf16x8*)&xi_res[(size_t)row*2048 + cc] = o;   // in-place into xi half
}

extern "C" void kernel_launch(void* const* d_in, const int* in_sizes, int n_in,
                              void* d_out, int out_size, void* d_ws, size_t ws_size,
                              hipStream_t stream)
{
  const float* x      = (const float*)d_in[0];
  const float* W_in   = (const float*)d_in[1];
  const float* conv_w = (const float*)d_in[2];
  const float* conv_b = (const float*)d_in[3];
  const float* W_x    = (const float*)d_in[4];
  const float* W_dt   = (const float*)d_in[5];
  const float* b_dt   = (const float*)d_in[6];
  const float* A_log  = (const float*)d_in[7];
  const float* D_param= (const float*)d_in[8];
  const float* W_out  = (const float*)d_in[9];
  float* out = (float*)d_out;
  char* ws = (char*)d_ws;

  if (ws_size < 121700352u) return;  // ~116 MB scratch

  const size_t MB = 1024*1024;
  bf16_t* x_bf    = (bf16_t*)(ws + 0);          // 16 MB, dead after gemm1
  float*  proj    = (float*) (ws + 0);          //  8 MB, overlays x_bf
  float*  y_state = (float*) (ws + 8*MB);       //  1 MB, overlays x_bf
  bf16_t* Win_bf  = (bf16_t*)(ws + 16*MB);      //  2 MB, dead after gemm1
  float2* aBu     = (float2*)(ws + 16*MB);      //  2 MB, overlays Win_bf
  bf16_t* Wout_bf = (bf16_t*)(ws + 18*MB);      //  1 MB
  bf16_t* Wcat_bf = (bf16_t*)(ws + 19*MB);      //  0.25 MB
  bf16_t* xi_res  = (bf16_t*)(ws + 20*MB);      // 64 MB (xi half reused as yfull)
  bf16_t* xa      = (bf16_t*)(ws + 84*MB);      // 32 MB
  float*  u       = (float*) (ws + 116*MB);     // 64 KB

  convert_kernel<<<dim3(9856), dim3(256), 0, stream>>>(x, W_in, W_out, W_dt, W_x,
                                                       x_bf, Win_bf, Wout_bf, Wcat_bf);
  gemm_bt<true ><<<dim3(128,16), dim3(256), 0, stream>>>(x_bf, Win_bf, (void*)xi_res, 512, 2048, 512);
  conv_kernel   <<<dim3(512), dim3(256), 0, stream>>>(xi_res, conv_w, conv_b, xa, u);
  gemm_bt<false><<<dim3(128,1), dim3(256), 0, stream>>>(xa, Wcat_bf, (void*)proj, 1024, 128, 1024);
  dt_kernel     <<<dim3(1024), dim3(256), 0, stream>>>(proj, u, b_dt, A_log, aBu);
  scan_kernel   <<<dim3(64), dim3(64), 0, stream>>>(aBu, y_state);
  yfull_kernel  <<<dim3(8192), dim3(256), 0, stream>>>(xa, xi_res, y_state, D_param);
  gemm_bt<false><<<dim3(128,4), dim3(256), 0, stream>>>(xi_res, Wout_bf, (void*)out, 2048, 512, 1024);
}

// Round 5
// 245.822 us; speedup vs baseline: 1.2218x; 1.0158x over previous
//
#include <hip/hip_runtime.h>
#include <stdint.h>

typedef __bf16 bf16_t;
typedef __bf16 bf16x8 __attribute__((ext_vector_type(8)));
typedef __bf16 bf16x4 __attribute__((ext_vector_type(4)));
typedef float  f32x4  __attribute__((ext_vector_type(4)));

#define AS1 __attribute__((address_space(1)))
#define AS3 __attribute__((address_space(3)))

#define SEQ   4096
#define DIMM  512
#define DIN   1024
#define ROWS  16384   // BATCH*SEQLEN

__device__ __forceinline__ void gload_lds16(const void* g, void* l) {
  __builtin_amdgcn_global_load_lds((AS1 void*)g, (AS3 void*)l, 16, 0, 0);
}

// ---------------- C = A (MxK, lda) * B^T (NxK packed), bf16 in, fp32 acc ----------------
// 128x128 tile, BK=64, 256 threads (4 waves, 2x2 of 64x64), mfma 16x16x32 bf16
// MODE: 0 = f32 C, 1 = bf16 C, 2 = fused dt/aBu epilogue (GEMM2)
template<int MODE>
__global__ void gemm_bt(const bf16_t* __restrict__ A, const bf16_t* __restrict__ B,
                        void* __restrict__ Cv, int lda, int N, int K,
                        const float* __restrict__ u_g, const float* __restrict__ b_dt_g,
                        const float* __restrict__ A_log_g)
{
  __shared__ __align__(16) bf16_t As[128*64];
  __shared__ __align__(16) bf16_t Bs[128*64];
  const int tid = threadIdx.x;
  const int l = tid & 63, w = tid >> 6;
  const int bm = blockIdx.x, bn = blockIdx.y;
  const bf16_t* Ab = A + (size_t)bm*128*lda;
  const bf16_t* Bb = B + (size_t)bn*128*K;
  f32x4 acc[4][4] = {};
  const int wr = (w>>1)*64, wc = (w&1)*64;
  const int lr = l & 15, lk = (l>>4)*8;
  const int srow = w*8 + (l>>3);   // row within each 32-row staging group
  const int scol = (l&7)*8;        // col (elements) within 64-wide K slice

  for (int kt = 0; kt < K; kt += 64) {
#pragma unroll
    for (int i = 0; i < 4; i++) {
      gload_lds16(Ab + (size_t)(i*32 + srow)*lda + kt + scol, As + i*2048 + w*512);
      gload_lds16(Bb + (size_t)(i*32 + srow)*K   + kt + scol, Bs + i*2048 + w*512);
    }
    __syncthreads();
#pragma unroll
    for (int kk = 0; kk < 2; kk++) {
      bf16x8 af[4], bv[4];
#pragma unroll
      for (int m = 0; m < 4; m++) af[m] = *(const bf16x8*)&As[(wr + m*16 + lr)*64 + kk*32 + lk];
#pragma unroll
      for (int n = 0; n < 4; n++) bv[n] = *(const bf16x8*)&Bs[(wc + n*16 + lr)*64 + kk*32 + lk];
#pragma unroll
      for (int m = 0; m < 4; m++)
#pragma unroll
        for (int n = 0; n < 4; n++)
          acc[m][n] = __builtin_amdgcn_mfma_f32_16x16x32_bf16(af[m], bv[n], acc[m][n], 0, 0, 0);
    }
    __syncthreads();
  }
  const int row0 = bm*128 + wr + (l>>4)*4;
  const int col0 = bn*128 + wc + lr;

  if constexpr (MODE == 2) {
    // fused dt/a/Bu epilogue: only cols 0..31 are real (dt = col lr, B = col 16+lr)
    if (wc == 0) {
      const float bdt  = b_dt_g[lr];
      const float Aexp = expf(A_log_g[lr]);
      float2* aBu = (float2*)Cv;
#pragma unroll
      for (int m = 0; m < 4; m++)
#pragma unroll
        for (int r = 0; r < 4; r++) {
          int row = row0 + m*16 + r;
          float xdt = acc[m][0][r] + bdt;
          float dt  = (xdt > 20.f) ? xdt : log1pf(expf(xdt));
          float a   = expf(-Aexp * dt);
          float Bu  = dt * acc[m][1][r] * u_g[row];
          int b = row >> 12, li = row & 4095;
          aBu[(size_t)((b<<4) + lr)*4096 + li] = make_float2(a, Bu);
        }
    }
    return;
  }

#pragma unroll
  for (int m = 0; m < 4; m++)
#pragma unroll
    for (int n = 0; n < 4; n++)
#pragma unroll
      for (int r = 0; r < 4; r++) {
        size_t idx = (size_t)(row0 + m*16 + r)*N + (col0 + n*16);
        if constexpr (MODE == 1) ((bf16_t*)Cv)[idx] = (bf16_t)acc[m][n][r];
        else                     ((float*)Cv)[idx]  = acc[m][n][r];
      }
}

// ---------------- fp32 -> bf16 conversions + packed W_dt/W_x[16:32] ----------------
__global__ __launch_bounds__(256) void convert_kernel(
    const float* __restrict__ x, const float* __restrict__ W_in,
    const float* __restrict__ W_out, const float* __restrict__ W_dt, const float* __restrict__ W_x,
    bf16_t* __restrict__ x_bf, bf16_t* __restrict__ Win_bf,
    bf16_t* __restrict__ Wout_bf, bf16_t* __restrict__ Wcat_bf)
{
  const size_t N0 = 8388608/4, N1 = N0 + 1048576/4, N2 = N1 + 524288/4, N3 = N2 + 131072/4;
  size_t i = (size_t)blockIdx.x*256 + threadIdx.x;
  bf16_t* dst; float4 v;
  if (i < N0)      { v = ((const float4*)x)[i];          dst = x_bf   + i*4; }
  else if (i < N1) { size_t j = i - N0; v = ((const float4*)W_in)[j];  dst = Win_bf  + j*4; }
  else if (i < N2) { size_t j = i - N1; v = ((const float4*)W_out)[j]; dst = Wout_bf + j*4; }
  else if (i < N3) {
    size_t j = i - N2; size_t el = j*4; int r = (int)(el >> 10), c = (int)(el & 1023);
    if (r < 16)      v = *(const float4*)(W_dt + r*1024 + c);
    else if (r < 32) v = *(const float4*)(W_x  + r*1024 + c);   // rows 16..31 = B_proj slice
    else             v = make_float4(0.f, 0.f, 0.f, 0.f);
    dst = Wcat_bf + el;
  } else return;
  bf16x4 o; o[0]=(bf16_t)v.x; o[1]=(bf16_t)v.y; o[2]=(bf16_t)v.z; o[3]=(bf16_t)v.w;
  *(bf16x4*)dst = o;
}

// ------------- depthwise causal conv(4) + bias + SiLU + u=mean(xa[:,:64]) -------------
// Team = 128 threads (8 ch/thread, 1024 ch) walking 16 consecutive rows of one batch.
// Ring invariant: slot(row index i) = i & 3.
#define CONV_T 16
__global__ __launch_bounds__(256) void conv_kernel(
    const bf16_t* __restrict__ xi_res, const float* __restrict__ conv_w,
    const float* __restrict__ conv_b, bf16_t* __restrict__ xa, float* __restrict__ u)
{
  const int team = blockIdx.x*2 + (threadIdx.x >> 7);   // 1024 teams
  const int t    = threadIdx.x & 127;
  const int b    = team >> 8;                           // 256 teams per batch
  const int r0   = (team & 255) * CONV_T;               // row within batch
  const int c0   = t * 8;

  float w[8][4], bias[8];
#pragma unroll
  for (int e = 0; e < 8; e++) {
    float4 v = *(const float4*)(conv_w + (size_t)(c0 + e)*4);
    w[e][0]=v.x; w[e][1]=v.y; w[e][2]=v.z; w[e][3]=v.w;
  }
  {
    float4 b0 = *(const float4*)(conv_b + c0);
    float4 b1 = *(const float4*)(conv_b + c0 + 4);
    bias[0]=b0.x; bias[1]=b0.y; bias[2]=b0.z; bias[3]=b0.w;
    bias[4]=b1.x; bias[5]=b1.y; bias[6]=b1.z; bias[7]=b1.w;
  }

  const bf16_t* xbase = xi_res + (size_t)b*SEQ*2048 + c0;
  bf16x8 win[4];
#pragma unroll
  for (int k = 0; k < 4; k++)
#pragma unroll
    for (int e = 0; e < 8; e++) win[k][e] = (bf16_t)0.f;

  // warmup: rows r0-3, r0-2, r0-1 -> slots 1, 2, 3
#pragma unroll
  for (int k = 1; k < 4; k++) {
    int lb = r0 - 4 + k;
    if (lb >= 0) win[k] = *(const bf16x8*)(xbase + (size_t)lb*2048);
  }

  const int growbase = b*SEQ + r0;
#pragma unroll
  for (int i = 0; i < CONV_T; i++) {
    win[i & 3] = *(const bf16x8*)(xbase + (size_t)(r0 + i)*2048);  // row r0+i -> slot i&3
    bf16x8 o;
    float usum = 0.f;
#pragma unroll
    for (int e = 0; e < 8; e++) {
      float acc = bias[e]
        + w[e][0]*(float)win[(i+1)&3][e]   // row r0+i-3
        + w[e][1]*(float)win[(i+2)&3][e]   // row r0+i-2
        + w[e][2]*(float)win[(i+3)&3][e]   // row r0+i-1
        + w[e][3]*(float)win[(i  )&3][e];  // row r0+i
      float sil = acc / (1.f + expf(-acc));
      usum += sil;
      o[e] = (bf16_t)sil;
    }
    *(bf16x8*)(xa + (size_t)(growbase + i)*DIN + c0) = o;
    if (t < 8) {
      usum += __shfl_xor(usum, 1, 64);
      usum += __shfl_xor(usum, 2, 64);
      usum += __shfl_xor(usum, 4, 64);
      if (t == 0) u[growbase + i] = usum * (1.f/64.f);
    }
  }
}

// ---------------- segmented scan over L=4096 per (b,n): 256 threads, 16 steps each ----------------
// aBu layout: [(b*16+n)][l] float2 (a, Bu).  y layout: [(b*16+n)][l] float.
__global__ __launch_bounds__(256) void scan_kernel(const float2* __restrict__ aBu, float* __restrict__ y)
{
  __shared__ float2 lds[4096 + 256];   // padded: phys(i) = i + i/16
  __shared__ float2 wtot[4];
  const int tid = threadIdx.x;
  const int bn = blockIdx.x;
  const float2* base = aBu + (size_t)bn*4096;

#pragma unroll
  for (int c = 0; c < 16; c++) {
    int i = c*256 + tid;
    lds[i + (i>>4)] = base[i];
  }
  __syncthreads();

  // local segment: P = prod a, S = local scan result at segment end (s_in = 0)
  const int p0 = tid*17;
  float P = 1.f, S = 0.f;
#pragma unroll
  for (int j = 0; j < 16; j++) {
    float2 ab = lds[p0 + j];
    S = S*ab.x + ab.y;
    P *= ab.x;
  }
  // wave-level inclusive scan of segment operators (compose prev-then-cur)
  float Pi = P, Si = S;
  const int l = tid & 63;
#pragma unroll
  for (int off = 1; off < 64; off <<= 1) {
    float Pp = __shfl_up(Pi, off, 64);
    float Sp = __shfl_up(Si, off, 64);
    if (l >= off) { Si = Sp*Pi + Si; Pi = Pp*Pi; }
  }
  const int w = tid >> 6;
  if (l == 63) wtot[w] = make_float2(Pi, Si);
  __syncthreads();

  // carry-in for this thread = compose(waves < w, lanes < l in wave); s0 = 0 -> s_in = S part
  float Pc = 1.f, Sc = 0.f;
  for (int k = 0; k < 4; k++)
    if (k < w) { Sc = Sc*wtot[k].x + wtot[k].y; Pc *= wtot[k].x; }
  float Pe = 1.f, Se = 0.f;
  {
    float Pp = __shfl_up(Pi, 1, 64);
    float Sp = __shfl_up(Si, 1, 64);
    if (l > 0) { Pe = Pp; Se = Sp; }
  }
  float s = Sc*Pe + Se;   // state after all previous segments (s0 = 0)

  // replay, storing y into .x
#pragma unroll
  for (int j = 0; j < 16; j++) {
    float2 ab = lds[p0 + j];
    s = s*ab.x + ab.y;
    lds[p0 + j].x = s;
  }
  __syncthreads();
  float* yb = y + (size_t)bn*4096;
#pragma unroll
  for (int c = 0; c < 16; c++) {
    int i = c*256 + tid;
    yb[i] = lds[i + (i>>4)].x;
  }
}

// ---------------- y_full = (y_rep + xa*D) * silu(res) -> written into xi half of xi_res ----------------
__global__ __launch_bounds__(256) void yfull_kernel(
    const bf16_t* __restrict__ xa, bf16_t* __restrict__ xi_res,
    const float* __restrict__ y_state, const float* __restrict__ D_param)
{
  int idx = blockIdx.x*256 + threadIdx.x;   // ROWS * 128 chunks of 8
  int row = idx >> 7, cc = (idx & 127)*8;
  bf16x8 xav  = *(const bf16x8*)&xa[(size_t)row*DIN + cc];
  bf16x8 resv = *(const bf16x8*)&xi_res[(size_t)row*2048 + DIN + cc];
  int b = row >> 12, li = row & 4095, n = cc >> 6;
  float ys = y_state[(size_t)((b<<4) + n)*4096 + li];
  float dp[8];
  float4 d0 = *(const float4*)(D_param + cc);
  float4 d1 = *(const float4*)(D_param + cc + 4);
  dp[0]=d0.x; dp[1]=d0.y; dp[2]=d0.z; dp[3]=d0.w; dp[4]=d1.x; dp[5]=d1.y; dp[6]=d1.z; dp[7]=d1.w;
  bf16x8 o;
#pragma unroll
  for (int e = 0; e < 8; e++) {
    float r = (float)resv[e];
    float sil = r / (1.f + expf(-r));
    float yv = (ys + (float)xav[e]*dp[e]) * sil;
    o[e] = (bf16_t)yv;
  }
  *(bf16x8*)&xi_res[(size_t)row*2048 + cc] = o;   // in-place into xi half
}

extern "C" void kernel_launch(void* const* d_in, const int* in_sizes, int n_in,
                              void* d_out, int out_size, void* d_ws, size_t ws_size,
                              hipStream_t stream)
{
  const float* x      = (const float*)d_in[0];
  const float* W_in   = (const float*)d_in[1];
  const float* conv_w = (const float*)d_in[2];
  const float* conv_b = (const float*)d_in[3];
  const float* W_x    = (const float*)d_in[4];
  const float* W_dt   = (const float*)d_in[5];
  const float* b_dt   = (const float*)d_in[6];
  const float* A_log  = (const float*)d_in[7];
  const float* D_param= (const float*)d_in[8];
  const float* W_out  = (const float*)d_in[9];
  float* out = (float*)d_out;
  char* ws = (char*)d_ws;

  if (ws_size < 121700352u) return;  // ~116 MB scratch

  const size_t MB = 1024*1024;
  bf16_t* x_bf    = (bf16_t*)(ws + 0);          // 16 MB, dead after gemm1
  float*  y_state = (float*) (ws + 8*MB);       //  1 MB, overlays x_bf upper half
  bf16_t* Win_bf  = (bf16_t*)(ws + 16*MB);      //  2 MB, dead after gemm1
  float2* aBu     = (float2*)(ws + 16*MB);      //  2 MB, overlays Win_bf
  bf16_t* Wout_bf = (bf16_t*)(ws + 18*MB);      //  1 MB
  bf16_t* Wcat_bf = (bf16_t*)(ws + 19*MB);      //  0.25 MB
  bf16_t* xi_res  = (bf16_t*)(ws + 20*MB);      // 64 MB (xi half reused as yfull)
  bf16_t* xa      = (bf16_t*)(ws + 84*MB);      // 32 MB
  float*  u       = (float*) (ws + 116*MB);     // 64 KB

  convert_kernel<<<dim3(9856), dim3(256), 0, stream>>>(x, W_in, W_out, W_dt, W_x,
                                                       x_bf, Win_bf, Wout_bf, Wcat_bf);
  gemm_bt<1><<<dim3(128,16), dim3(256), 0, stream>>>(x_bf, Win_bf, (void*)xi_res, 512, 2048, 512,
                                                     nullptr, nullptr, nullptr);
  conv_kernel<<<dim3(512), dim3(256), 0, stream>>>(xi_res, conv_w, conv_b, xa, u);
  gemm_bt<2><<<dim3(128,1), dim3(256), 0, stream>>>(xa, Wcat_bf, (void*)aBu, 1024, 128, 1024,
                                                    u, b_dt, A_log);
  scan_kernel<<<dim3(64), dim3(256), 0, stream>>>(aBu, y_state);
  yfull_kernel<<<dim3(8192), dim3(256), 0, stream>>>(xa, xi_res, y_state, D_param);
  gemm_bt<0><<<dim3(128,4), dim3(256), 0, stream>>>(xi_res, Wout_bf, (void*)out, 2048, 512, 1024,
                                                    nullptr, nullptr, nullptr);
}

// Round 6
// 237.431 us; speedup vs baseline: 1.2650x; 1.0353x over previous
//
#include <hip/hip_runtime.h>
#include <stdint.h>

typedef __bf16 bf16_t;
typedef __bf16 bf16x8 __attribute__((ext_vector_type(8)));
typedef __bf16 bf16x4 __attribute__((ext_vector_type(4)));
typedef float  f32x4  __attribute__((ext_vector_type(4)));

#define AS1 __attribute__((address_space(1)))
#define AS3 __attribute__((address_space(3)))

#define SEQ   4096
#define DIMM  512
#define DIN   1024
#define ROWS  16384   // BATCH*SEQLEN

__device__ __forceinline__ void gload_lds16(const void* g, void* l) {
  __builtin_amdgcn_global_load_lds((AS1 void*)g, (AS3 void*)l, 16, 0, 0);
}

// ---------------- C = A (MxK, lda) * B^T (NxK packed), bf16 in, fp32 acc ----------------
// 128x128 tile, BK=64, 256 threads (4 waves, 2x2 of 64x64), mfma 16x16x32 bf16
// MODE: 0 = f32 C, 1 = bf16 C, 2 = fused dt/aBu epilogue (GEMM2)
template<int MODE>
__global__ void gemm_bt(const bf16_t* __restrict__ A, const bf16_t* __restrict__ B,
                        void* __restrict__ Cv, int lda, int N, int K,
                        const float* __restrict__ u_g, const float* __restrict__ b_dt_g,
                        const float* __restrict__ A_log_g)
{
  __shared__ __align__(16) bf16_t As[128*64];
  __shared__ __align__(16) bf16_t Bs[128*64];
  const int tid = threadIdx.x;
  const int l = tid & 63, w = tid >> 6;
  const int bm = blockIdx.x, bn = blockIdx.y;
  const bf16_t* Ab = A + (size_t)bm*128*lda;
  const bf16_t* Bb = B + (size_t)bn*128*K;
  f32x4 acc[4][4] = {};
  const int wr = (w>>1)*64, wc = (w&1)*64;
  const int lr = l & 15, lk = (l>>4)*8;
  const int srow = w*8 + (l>>3);   // row within each 32-row staging group
  const int scol = (l&7)*8;        // col (elements) within 64-wide K slice

  for (int kt = 0; kt < K; kt += 64) {
#pragma unroll
    for (int i = 0; i < 4; i++) {
      gload_lds16(Ab + (size_t)(i*32 + srow)*lda + kt + scol, As + i*2048 + w*512);
      gload_lds16(Bb + (size_t)(i*32 + srow)*K   + kt + scol, Bs + i*2048 + w*512);
    }
    __syncthreads();
#pragma unroll
    for (int kk = 0; kk < 2; kk++) {
      bf16x8 af[4], bv[4];
#pragma unroll
      for (int m = 0; m < 4; m++) af[m] = *(const bf16x8*)&As[(wr + m*16 + lr)*64 + kk*32 + lk];
#pragma unroll
      for (int n = 0; n < 4; n++) bv[n] = *(const bf16x8*)&Bs[(wc + n*16 + lr)*64 + kk*32 + lk];
#pragma unroll
      for (int m = 0; m < 4; m++)
#pragma unroll
        for (int n = 0; n < 4; n++)
          acc[m][n] = __builtin_amdgcn_mfma_f32_16x16x32_bf16(af[m], bv[n], acc[m][n], 0, 0, 0);
    }
    __syncthreads();
  }
  const int row0 = bm*128 + wr + (l>>4)*4;
  const int col0 = bn*128 + wc + lr;

  if constexpr (MODE == 2) {
    // fused dt/a/Bu epilogue: only cols 0..31 are real (dt = col lr, B = col 16+lr)
    if (wc == 0) {
      const float bdt  = b_dt_g[lr];
      const float Aexp = expf(A_log_g[lr]);
      float2* aBu = (float2*)Cv;
#pragma unroll
      for (int m = 0; m < 4; m++)
#pragma unroll
        for (int r = 0; r < 4; r++) {
          int row = row0 + m*16 + r;
          float xdt = acc[m][0][r] + bdt;
          float dt  = (xdt > 20.f) ? xdt : log1pf(expf(xdt));
          float a   = expf(-Aexp * dt);
          float Bu  = dt * acc[m][1][r] * u_g[row];
          int b = row >> 12, li = row & 4095;
          aBu[(size_t)((b<<4) + lr)*4096 + li] = make_float2(a, Bu);
        }
    }
    return;
  }

#pragma unroll
  for (int m = 0; m < 4; m++)
#pragma unroll
    for (int n = 0; n < 4; n++)
#pragma unroll
      for (int r = 0; r < 4; r++) {
        size_t idx = (size_t)(row0 + m*16 + r)*N + (col0 + n*16);
        if constexpr (MODE == 1) ((bf16_t*)Cv)[idx] = (bf16_t)acc[m][n][r];
        else                     ((float*)Cv)[idx]  = acc[m][n][r];
      }
}

// ---------------- fp32 -> bf16 conversions + packed W_dt/W_x[16:32] ----------------
__global__ __launch_bounds__(256) void convert_kernel(
    const float* __restrict__ x, const float* __restrict__ W_in,
    const float* __restrict__ W_out, const float* __restrict__ W_dt, const float* __restrict__ W_x,
    bf16_t* __restrict__ x_bf, bf16_t* __restrict__ Win_bf,
    bf16_t* __restrict__ Wout_bf, bf16_t* __restrict__ Wcat_bf)
{
  const size_t N0 = 8388608/4, N1 = N0 + 1048576/4, N2 = N1 + 524288/4, N3 = N2 + 131072/4;
  size_t i = (size_t)blockIdx.x*256 + threadIdx.x;
  bf16_t* dst; float4 v;
  if (i < N0)      { v = ((const float4*)x)[i];          dst = x_bf   + i*4; }
  else if (i < N1) { size_t j = i - N0; v = ((const float4*)W_in)[j];  dst = Win_bf  + j*4; }
  else if (i < N2) { size_t j = i - N1; v = ((const float4*)W_out)[j]; dst = Wout_bf + j*4; }
  else if (i < N3) {
    size_t j = i - N2; size_t el = j*4; int r = (int)(el >> 10), c = (int)(el & 1023);
    if (r < 16)      v = *(const float4*)(W_dt + r*1024 + c);
    else if (r < 32) v = *(const float4*)(W_x  + r*1024 + c);   // rows 16..31 = B_proj slice
    else             v = make_float4(0.f, 0.f, 0.f, 0.f);
    dst = Wcat_bf + el;
  } else return;
  bf16x4 o; o[0]=(bf16_t)v.x; o[1]=(bf16_t)v.y; o[2]=(bf16_t)v.z; o[3]=(bf16_t)v.w;
  *(bf16x4*)dst = o;
}

// ------------- depthwise causal conv(4) + bias + SiLU + u=mean(xa[:,:64]) -------------
// Team = 128 threads (8 ch/thread). Each team computes CONV_R=4 consecutive rows.
// All 7 row-vectors loaded upfront into distinct registers (no ring reuse -> full ILP),
// 4096 teams -> 2048 blocks for latency-tolerant occupancy.
#define CONV_R 4
__global__ __launch_bounds__(256) void conv_kernel(
    const bf16_t* __restrict__ xi_res, const float* __restrict__ conv_w,
    const float* __restrict__ conv_b, bf16_t* __restrict__ xa, float* __restrict__ u)
{
  const int team = blockIdx.x*2 + (threadIdx.x >> 7);   // 4096 teams
  const int t    = threadIdx.x & 127;
  const int b    = team >> 10;                          // 1024 teams per batch
  const int r0   = (team & 1023) * CONV_R;              // row within batch
  const int c0   = t * 8;

  float w[8][4], bias[8];
#pragma unroll
  for (int e = 0; e < 8; e++) {
    float4 v = *(const float4*)(conv_w + (size_t)(c0 + e)*4);
    w[e][0]=v.x; w[e][1]=v.y; w[e][2]=v.z; w[e][3]=v.w;
  }
  {
    float4 b0 = *(const float4*)(conv_b + c0);
    float4 b1 = *(const float4*)(conv_b + c0 + 4);
    bias[0]=b0.x; bias[1]=b0.y; bias[2]=b0.z; bias[3]=b0.w;
    bias[4]=b1.x; bias[5]=b1.y; bias[6]=b1.z; bias[7]=b1.w;
  }

  // rowv[k] = row r0-3+k  (k = 0..6), all loads issued before compute
  const bf16_t* xbase = xi_res + ((size_t)b*SEQ + r0)*2048 + c0;
  bf16x8 rowv[CONV_R + 3];
#pragma unroll
  for (int k = 0; k < 3; k++) {
#pragma unroll
    for (int e = 0; e < 8; e++) rowv[k][e] = (bf16_t)0.f;
    if (r0 - 3 + k >= 0) rowv[k] = *(const bf16x8*)(xbase + (k - 3)*2048);
  }
#pragma unroll
  for (int k = 0; k < CONV_R; k++)
    rowv[3 + k] = *(const bf16x8*)(xbase + k*2048);

  const int growbase = b*SEQ + r0;
#pragma unroll
  for (int i = 0; i < CONV_R; i++) {
    bf16x8 o;
    float usum = 0.f;
#pragma unroll
    for (int e = 0; e < 8; e++) {
      float acc = bias[e]
        + w[e][0]*(float)rowv[i  ][e]   // row r0+i-3
        + w[e][1]*(float)rowv[i+1][e]   // row r0+i-2
        + w[e][2]*(float)rowv[i+2][e]   // row r0+i-1
        + w[e][3]*(float)rowv[i+3][e];  // row r0+i
      float sil = acc / (1.f + expf(-acc));
      usum += sil;
      o[e] = (bf16_t)sil;
    }
    *(bf16x8*)(xa + (size_t)(growbase + i)*DIN + c0) = o;
    if (t < 8) {
      usum += __shfl_xor(usum, 1, 64);
      usum += __shfl_xor(usum, 2, 64);
      usum += __shfl_xor(usum, 4, 64);
      if (t == 0) u[growbase + i] = usum * (1.f/64.f);
    }
  }
}

// ---------------- segmented scan over L=4096 per (b,n): 256 threads, 16 steps each ----------------
// aBu layout: [(b*16+n)][l] float2 (a, Bu).  y layout: [(b*16+n)][l] float.
__global__ __launch_bounds__(256) void scan_kernel(const float2* __restrict__ aBu, float* __restrict__ y)
{
  __shared__ float2 lds[4096 + 256];   // padded: phys(i) = i + i/16
  __shared__ float2 wtot[4];
  const int tid = threadIdx.x;
  const int bn = blockIdx.x;
  const float2* base = aBu + (size_t)bn*4096;

#pragma unroll
  for (int c = 0; c < 16; c++) {
    int i = c*256 + tid;
    lds[i + (i>>4)] = base[i];
  }
  __syncthreads();

  // local segment: P = prod a, S = local scan result at segment end (s_in = 0)
  const int p0 = tid*17;
  float P = 1.f, S = 0.f;
#pragma unroll
  for (int j = 0; j < 16; j++) {
    float2 ab = lds[p0 + j];
    S = S*ab.x + ab.y;
    P *= ab.x;
  }
  // wave-level inclusive scan of segment operators (compose prev-then-cur)
  float Pi = P, Si = S;
  const int l = tid & 63;
#pragma unroll
  for (int off = 1; off < 64; off <<= 1) {
    float Pp = __shfl_up(Pi, off, 64);
    float Sp = __shfl_up(Si, off, 64);
    if (l >= off) { Si = Sp*Pi + Si; Pi = Pp*Pi; }
  }
  const int w = tid >> 6;
  if (l == 63) wtot[w] = make_float2(Pi, Si);
  __syncthreads();

  // carry-in for this thread = compose(waves < w, lanes < l in wave); s0 = 0 -> s_in = S part
  float Pc = 1.f, Sc = 0.f;
  for (int k = 0; k < 4; k++)
    if (k < w) { Sc = Sc*wtot[k].x + wtot[k].y; Pc *= wtot[k].x; }
  float Pe = 1.f, Se = 0.f;
  {
    float Pp = __shfl_up(Pi, 1, 64);
    float Sp = __shfl_up(Si, 1, 64);
    if (l > 0) { Pe = Pp; Se = Sp; }
  }
  float s = Sc*Pe + Se;   // state after all previous segments (s0 = 0)

  // replay, storing y into .x
#pragma unroll
  for (int j = 0; j < 16; j++) {
    float2 ab = lds[p0 + j];
    s = s*ab.x + ab.y;
    lds[p0 + j].x = s;
  }
  __syncthreads();
  float* yb = y + (size_t)bn*4096;
#pragma unroll
  for (int c = 0; c < 16; c++) {
    int i = c*256 + tid;
    yb[i] = lds[i + (i>>4)].x;
  }
}

// ---------------- y_full = (y_rep + xa*D) * silu(res) -> written into xi half of xi_res ----------------
__global__ __launch_bounds__(256) void yfull_kernel(
    const bf16_t* __restrict__ xa, bf16_t* __restrict__ xi_res,
    const float* __restrict__ y_state, const float* __restrict__ D_param)
{
  int idx = blockIdx.x*256 + threadIdx.x;   // ROWS * 128 chunks of 8
  int row = idx >> 7, cc = (idx & 127)*8;
  bf16x8 xav  = *(const bf16x8*)&xa[(size_t)row*DIN + cc];
  bf16x8 resv = *(const bf16x8*)&xi_res[(size_t)row*2048 + DIN + cc];
  int b = row >> 12, li = row & 4095, n = cc >> 6;
  float ys = y_state[(size_t)((b<<4) + n)*4096 + li];
  float dp[8];
  float4 d0 = *(const float4*)(D_param + cc);
  float4 d1 = *(const float4*)(D_param + cc + 4);
  dp[0]=d0.x; dp[1]=d0.y; dp[2]=d0.z; dp[3]=d0.w; dp[4]=d1.x; dp[5]=d1.y; dp[6]=d1.z; dp[7]=d1.w;
  bf16x8 o;
#pragma unroll
  for (int e = 0; e < 8; e++) {
    float r = (float)resv[e];
    float sil = r / (1.f + expf(-r));
    float yv = (ys + (float)xav[e]*dp[e]) * sil;
    o[e] = (bf16_t)yv;
  }
  *(bf16x8*)&xi_res[(size_t)row*2048 + cc] = o;   // in-place into xi half
}

extern "C" void kernel_launch(void* const* d_in, const int* in_sizes, int n_in,
                              void* d_out, int out_size, void* d_ws, size_t ws_size,
                              hipStream_t stream)
{
  const float* x      = (const float*)d_in[0];
  const float* W_in   = (const float*)d_in[1];
  const float* conv_w = (const float*)d_in[2];
  const float* conv_b = (const float*)d_in[3];
  const float* W_x    = (const float*)d_in[4];
  const float* W_dt   = (const float*)d_in[5];
  const float* b_dt   = (const float*)d_in[6];
  const float* A_log  = (const float*)d_in[7];
  const float* D_param= (const float*)d_in[8];
  const float* W_out  = (const float*)d_in[9];
  float* out = (float*)d_out;
  char* ws = (char*)d_ws;

  if (ws_size < 121700352u) return;  // ~116 MB scratch

  const size_t MB = 1024*1024;
  bf16_t* x_bf    = (bf16_t*)(ws + 0);          // 16 MB, dead after gemm1
  float*  y_state = (float*) (ws + 8*MB);       //  1 MB, overlays x_bf upper half
  bf16_t* Win_bf  = (bf16_t*)(ws + 16*MB);      //  2 MB, dead after gemm1
  float2* aBu     = (float2*)(ws + 16*MB);      //  2 MB, overlays Win_bf
  bf16_t* Wout_bf = (bf16_t*)(ws + 18*MB);      //  1 MB
  bf16_t* Wcat_bf = (bf16_t*)(ws + 19*MB);      //  0.25 MB
  bf16_t* xi_res  = (bf16_t*)(ws + 20*MB);      // 64 MB (xi half reused as yfull)
  bf16_t* xa      = (bf16_t*)(ws + 84*MB);      // 32 MB
  float*  u       = (float*) (ws + 116*MB);     // 64 KB

  convert_kernel<<<dim3(9856), dim3(256), 0, stream>>>(x, W_in, W_out, W_dt, W_x,
                                                       x_bf, Win_bf, Wout_bf, Wcat_bf);
  gemm_bt<1><<<dim3(128,16), dim3(256), 0, stream>>>(x_bf, Win_bf, (void*)xi_res, 512, 2048, 512,
                                                     nullptr, nullptr, nullptr);
  conv_kernel<<<dim3(2048), dim3(256), 0, stream>>>(xi_res, conv_w, conv_b, xa, u);
  gemm_bt<2><<<dim3(128,1), dim3(256), 0, stream>>>(xa, Wcat_bf, (void*)aBu, 1024, 128, 1024,
                                                    u, b_dt, A_log);
  scan_kernel<<<dim3(64), dim3(256), 0, stream>>>(aBu, y_state);
  yfull_kernel<<<dim3(8192), dim3(256), 0, stream>>>(xa, xi_res, y_state, D_param);
  gemm_bt<0><<<dim3(128,4), dim3(256), 0, stream>>>(xi_res, Wout_bf, (void*)out, 2048, 512, 1024,
                                                    nullptr, nullptr, nullptr);
}